// Round 1
// baseline (315.898 us; speedup 1.0000x reference)
//
#include <hip/hip_runtime.h>

#define NB 256   // batch
#define NN 360   // nodes
#define NPAD 384 // padded nodes (12*32)
#define NF 360   // nfeat
#define NH 128   // nhid

using bf16x8 = __attribute__((ext_vector_type(8))) short;
using f32x4  = __attribute__((ext_vector_type(4))) float;

static __device__ __forceinline__ unsigned short f2bf(float f) {
  union { float f; unsigned u; } v; v.f = f;
  unsigned r = v.u + 0x7FFFu + ((v.u >> 16) & 1u);  // RNE
  return (unsigned short)(r >> 16);
}

static __device__ __forceinline__ bf16x8 cvt8(const float* __restrict__ p) {
  float4 a = *(const float4*)p;
  float4 b = *(const float4*)(p + 4);
  bf16x8 r;
  r[0] = (short)f2bf(a.x); r[1] = (short)f2bf(a.y);
  r[2] = (short)f2bf(a.z); r[3] = (short)f2bf(a.w);
  r[4] = (short)f2bf(b.x); r[5] = (short)f2bf(b.y);
  r[6] = (short)f2bf(b.z); r[7] = (short)f2bf(b.w);
  return r;
}

// ---------------- K0: W1T[h][k]=W1[k][h] (bf16, k-padded), W2T[n][k]=W2[k][n], zero gh ----
__global__ void k_prep(const float* __restrict__ W1, const float* __restrict__ W2,
                       unsigned short* __restrict__ W1T, unsigned short* __restrict__ W2T,
                       float* __restrict__ gh) {
  const int t = blockIdx.x * blockDim.x + threadIdx.x;
  if (t < NH * NPAD) {
    const int h = t / NPAD, k = t % NPAD;
    W1T[t] = (k < NF) ? f2bf(W1[k * NH + h]) : (unsigned short)0;
  } else if (t < NH * NPAD + NH * NH) {
    const int t2 = t - NH * NPAD;
    const int n = t2 / NH, k = t2 % NH;
    W2T[t2] = f2bf(W2[k * NH + n]);
  } else if (t < NH * NPAD + NH * NH + NB * 256) {
    gh[t - (NH * NPAD + NH * NH)] = 0.f;
  }
}

// ---------------- K1: XW1T[b][h][m] = (x@W1)^T, bf16, m padded&zeroed to 384 -------------
__global__ __launch_bounds__(256) void k_xw1(const float* __restrict__ x,
                                             const unsigned short* __restrict__ W1T,
                                             unsigned short* __restrict__ XW1T) {
  const int b   = blockIdx.x / 6;
  const int mt  = blockIdx.x % 6;
  const int wid = threadIdx.x >> 6;
  const int lane = threadIdx.x & 63;
  const int l15 = lane & 15, lg = lane >> 4;
  const int m   = mt * 64 + wid * 16 + l15;          // x row == output column
  const int mld = m < NN ? m : NN - 1;
  const float* xrow = x + ((size_t)b * NN + mld) * NF;

  const f32x4 fz = {0.f, 0.f, 0.f, 0.f};
  f32x4 acc[8];
#pragma unroll
  for (int i = 0; i < 8; ++i) acc[i] = fz;

  for (int ks = 0; ks < 12; ++ks) {
    const int k0 = ks * 32 + lg * 8;
    bf16x8 bfrag = {0, 0, 0, 0, 0, 0, 0, 0};
    if (k0 + 8 <= NF) bfrag = cvt8(xrow + k0);       // tail chunk 352..359 is exactly 8
#pragma unroll
    for (int hi = 0; hi < 8; ++hi) {
      bf16x8 afrag = *(const bf16x8*)(W1T + (hi * 16 + l15) * NPAD + k0);
      acc[hi] = __builtin_amdgcn_mfma_f32_16x16x32_bf16(afrag, bfrag, acc[hi], 0, 0, 0);
    }
  }
  // D[h_local][m]: h = hi*16 + lg*4 + r, col = l15-mapped m
  unsigned short* ob = XW1T + (size_t)b * NH * NPAD + m;
  const bool valid = (m < NN);
#pragma unroll
  for (int hi = 0; hi < 8; ++hi) {
#pragma unroll
    for (int r = 0; r < 4; ++r) {
      const int h = hi * 16 + lg * 4 + r;
      ob[h * NPAD] = valid ? f2bf(acc[hi][r]) : (unsigned short)0;
      (void)h;
    }
  }
}

// ---------------- K2: H1 = relu(adj@XW1 + b1); gh1 += colsum; H1W2T = (H1@W2)^T ----------
__global__ __launch_bounds__(256) void k_h1(const float* __restrict__ adj,
                                            const unsigned short* __restrict__ XW1T,
                                            const unsigned short* __restrict__ W2T,
                                            const float* __restrict__ b1,
                                            unsigned short* __restrict__ H1W2T,
                                            float* __restrict__ gh) {
  const int b   = blockIdx.x / 6;
  const int mt  = blockIdx.x % 6;
  const int wid = threadIdx.x >> 6;
  const int lane = threadIdx.x & 63;
  const int l15 = lane & 15, lg = lane >> 4;
  const int arowi  = mt * 64 + wid * 16 + l15;       // adj row (== output row group)
  const int arowld = arowi < NN ? arowi : NN - 1;
  const float* arow = adj + ((size_t)b * NN + arowld) * NN;
  const unsigned short* xw = XW1T + (size_t)b * NH * NPAD;

  const f32x4 fz = {0.f, 0.f, 0.f, 0.f};
  f32x4 acc[8];
#pragma unroll
  for (int i = 0; i < 8; ++i) acc[i] = fz;

  for (int ks = 0; ks < 12; ++ks) {
    const int k0 = ks * 32 + lg * 8;
    bf16x8 afrag = {0, 0, 0, 0, 0, 0, 0, 0};
    if (k0 + 8 <= NN) afrag = cvt8(arow + k0);
#pragma unroll
    for (int ni = 0; ni < 8; ++ni) {
      bf16x8 bfrag = *(const bf16x8*)(xw + (ni * 16 + l15) * NPAD + k0);
      acc[ni] = __builtin_amdgcn_mfma_f32_16x16x32_bf16(afrag, bfrag, acc[ni], 0, 0, 0);
    }
  }

  // epilogue: bias + relu + row-mask; stash H1 (bf16) in wave-private LDS; gh1 col-sums
  __shared__ unsigned short h1s[4][16][NH];          // 16 KB
  float* ghb = gh + b * 256;
#pragma unroll
  for (int ni = 0; ni < 8; ++ni) {
    const int col = ni * 16 + l15;
    const float bias = b1[col];
    f32x4 v = acc[ni];
    float s = 0.f;
#pragma unroll
    for (int r = 0; r < 4; ++r) {
      const int orow = mt * 64 + wid * 16 + lg * 4 + r;
      float h = v[r] + bias;
      h = h > 0.f ? h : 0.f;
      if (orow >= NN) h = 0.f;
      h1s[wid][lg * 4 + r][col] = f2bf(h);
      s += h;
    }
    s += __shfl_xor(s, 16);
    s += __shfl_xor(s, 32);
    if (lg == 0) atomicAdd(&ghb[col], s);
  }
  __syncthreads();

  // second GEMM: (H1 16x128) @ (W2 128x128), K fully in-wave
  f32x4 acc2[8];
#pragma unroll
  for (int i = 0; i < 8; ++i) acc2[i] = fz;
#pragma unroll
  for (int ks = 0; ks < 4; ++ks) {
    const int k0 = ks * 32 + lg * 8;
    bf16x8 afrag = *(const bf16x8*)&h1s[wid][l15][k0];
#pragma unroll
    for (int ni = 0; ni < 8; ++ni) {
      bf16x8 bfrag = *(const bf16x8*)(W2T + (ni * 16 + l15) * NH + k0);
      acc2[ni] = __builtin_amdgcn_mfma_f32_16x16x32_bf16(afrag, bfrag, acc2[ni], 0, 0, 0);
    }
  }
  unsigned short* ob = H1W2T + (size_t)b * NH * NPAD;
#pragma unroll
  for (int ni = 0; ni < 8; ++ni) {
    const int h = ni * 16 + l15;
#pragma unroll
    for (int r = 0; r < 4; ++r) {
      const int m = mt * 64 + wid * 16 + lg * 4 + r;  // masked rows were zeroed -> stores 0
      ob[h * NPAD + m] = f2bf(acc2[ni][r]);
    }
  }
}

// ---------------- K3: H2 = relu(adj@H1W2 + b2) -> out f32; gh2 += colsum -----------------
__global__ __launch_bounds__(256) void k_h2(const float* __restrict__ adj,
                                            const unsigned short* __restrict__ H1W2T,
                                            const float* __restrict__ b2,
                                            float* __restrict__ out,
                                            float* __restrict__ gh) {
  const int b   = blockIdx.x / 6;
  const int mt  = blockIdx.x % 6;
  const int wid = threadIdx.x >> 6;
  const int lane = threadIdx.x & 63;
  const int l15 = lane & 15, lg = lane >> 4;
  const int arowi  = mt * 64 + wid * 16 + l15;
  const int arowld = arowi < NN ? arowi : NN - 1;
  const float* arow = adj + ((size_t)b * NN + arowld) * NN;
  const unsigned short* hw = H1W2T + (size_t)b * NH * NPAD;

  const f32x4 fz = {0.f, 0.f, 0.f, 0.f};
  f32x4 acc[8];
#pragma unroll
  for (int i = 0; i < 8; ++i) acc[i] = fz;

  for (int ks = 0; ks < 12; ++ks) {
    const int k0 = ks * 32 + lg * 8;
    bf16x8 afrag = {0, 0, 0, 0, 0, 0, 0, 0};
    if (k0 + 8 <= NN) afrag = cvt8(arow + k0);
#pragma unroll
    for (int ni = 0; ni < 8; ++ni) {
      bf16x8 bfrag = *(const bf16x8*)(hw + (ni * 16 + l15) * NPAD + k0);
      acc[ni] = __builtin_amdgcn_mfma_f32_16x16x32_bf16(afrag, bfrag, acc[ni], 0, 0, 0);
    }
  }

  float* ghb  = gh + b * 256 + 128;
  float* outb = out + (size_t)b * NN * NH;
#pragma unroll
  for (int ni = 0; ni < 8; ++ni) {
    const int col = ni * 16 + l15;
    const float bias = b2[col];
    f32x4 v = acc[ni];
    float s = 0.f;
#pragma unroll
    for (int r = 0; r < 4; ++r) {
      const int orow = mt * 64 + wid * 16 + lg * 4 + r;
      float h = v[r] + bias;
      h = h > 0.f ? h : 0.f;
      if (orow < NN) {
        outb[orow * NH + col] = h;
        s += h;
      }
    }
    s += __shfl_xor(s, 16);
    s += __shfl_xor(s, 32);
    if (lg == 0) atomicAdd(&ghb[col], s);
  }
}

extern "C" void kernel_launch(void* const* d_in, const int* in_sizes, int n_in,
                              void* d_out, int out_size, void* d_ws, size_t ws_size,
                              hipStream_t stream) {
  const float* x   = (const float*)d_in[0];
  const float* adj = (const float*)d_in[1];
  const float* W1  = (const float*)d_in[2];
  const float* b1  = (const float*)d_in[3];
  const float* W2  = (const float*)d_in[4];
  const float* b2  = (const float*)d_in[5];
  float* out = (float*)d_out;                         // h2 [256,360,128] then gh [256,256]
  float* gh  = out + (size_t)NB * NN * NH;

  char* ws = (char*)d_ws;
  // ws layout (bf16): XW1T [256][128][384] | H1W2T [256][128][384] | W1T [128][384] | W2T [128][128]
  unsigned short* XW1T  = (unsigned short*)ws;                          // 25,165,824 B
  unsigned short* H1W2T = (unsigned short*)(ws + 25165824);             // 25,165,824 B
  unsigned short* W1T   = (unsigned short*)(ws + 50331648);             //     98,304 B
  unsigned short* W2T   = (unsigned short*)(ws + 50331648 + 98304);     //     32,768 B

  k_prep<<<512, 256, 0, stream>>>(W1, W2, W1T, W2T, gh);
  k_xw1 <<<NB * 6, 256, 0, stream>>>(x, W1T, XW1T);
  k_h1  <<<NB * 6, 256, 0, stream>>>(adj, XW1T, W2T, b1, H1W2T, gh);
  k_h2  <<<NB * 6, 256, 0, stream>>>(adj, H1W2T, b2, out, gh);
}

// Round 2
// 311.593 us; speedup vs baseline: 1.0138x; 1.0138x over previous
//
#include <hip/hip_runtime.h>

#define NB 256   // batch
#define NN 360   // nodes
#define NPAD 384 // padded nodes / feats (12*32)
#define NF 360   // nfeat
#define NH 128   // nhid

using bf16x8 = __attribute__((ext_vector_type(8))) short;
using f32x4  = __attribute__((ext_vector_type(4))) float;

static __device__ __forceinline__ unsigned short f2bf(float f) {
  union { float f; unsigned u; } v; v.f = f;
  unsigned r = v.u + 0x7FFFu + ((v.u >> 16) & 1u);  // RNE
  return (unsigned short)(r >> 16);
}

static __device__ __forceinline__ bf16x8 cvt8(const float* __restrict__ p) {
  float4 a = *(const float4*)p;
  float4 b = *(const float4*)(p + 4);
  bf16x8 r;
  r[0] = (short)f2bf(a.x); r[1] = (short)f2bf(a.y);
  r[2] = (short)f2bf(a.z); r[3] = (short)f2bf(a.w);
  r[4] = (short)f2bf(b.x); r[5] = (short)f2bf(b.y);
  r[6] = (short)f2bf(b.z); r[7] = (short)f2bf(b.w);
  return r;
}

// ---------------- K0: W1T[h][k]=W1[k][h] (bf16, k-padded), W2T[n][k]=W2[k][n], zero gh ----
__global__ void k_prep(const float* __restrict__ W1, const float* __restrict__ W2,
                       unsigned short* __restrict__ W1T, unsigned short* __restrict__ W2T,
                       float* __restrict__ gh) {
  const int t = blockIdx.x * blockDim.x + threadIdx.x;
  if (t < NH * NPAD) {
    const int h = t / NPAD, k = t % NPAD;
    W1T[t] = (k < NF) ? f2bf(W1[k * NH + h]) : (unsigned short)0;
  } else if (t < NH * NPAD + NH * NH) {
    const int t2 = t - NH * NPAD;
    const int n = t2 / NH, k = t2 % NH;
    W2T[t2] = f2bf(W2[k * NH + n]);
  } else if (t < NH * NPAD + NH * NH + NB * 256) {
    gh[t - (NH * NPAD + NH * NH)] = 0.f;
  }
}

// ---------------- K1: XW1T[b][h][m] = (x@W1)^T, bf16, m padded&zeroed to 384 -------------
__global__ __launch_bounds__(256) void k_xw1(const float* __restrict__ x,
                                             const unsigned short* __restrict__ W1T,
                                             unsigned short* __restrict__ XW1T) {
  const int b   = blockIdx.x / 6;
  const int mt  = blockIdx.x % 6;
  const int wid = threadIdx.x >> 6;
  const int lane = threadIdx.x & 63;
  const int l15 = lane & 15, lg = lane >> 4;
  const int m   = mt * 64 + wid * 16 + l15;          // x row == output column
  const int mld = m < NN ? m : NN - 1;
  const float* xrow = x + ((size_t)b * NN + mld) * NF;

  // hoist per-lane x row into regs (bf16) — one latency exposure
  const bf16x8 bz = {0, 0, 0, 0, 0, 0, 0, 0};
  bf16x8 breg[12];
#pragma unroll
  for (int ks = 0; ks < 12; ++ks) {
    const int k0 = ks * 32 + lg * 8;
    breg[ks] = (k0 + 8 <= NF) ? cvt8(xrow + k0) : bz;
  }

  const f32x4 fz = {0.f, 0.f, 0.f, 0.f};
  f32x4 acc[8];
#pragma unroll
  for (int i = 0; i < 8; ++i) acc[i] = fz;

#pragma unroll
  for (int ks = 0; ks < 12; ++ks) {
    const int k0 = ks * 32 + lg * 8;
    bf16x8 af[8];
#pragma unroll
    for (int hi = 0; hi < 8; ++hi)
      af[hi] = *(const bf16x8*)(W1T + (hi * 16 + l15) * NPAD + k0);
#pragma unroll
    for (int hi = 0; hi < 8; ++hi)
      acc[hi] = __builtin_amdgcn_mfma_f32_16x16x32_bf16(af[hi], breg[ks], acc[hi], 0, 0, 0);
  }

  unsigned short* ob = XW1T + (size_t)b * NH * NPAD + m;
  const bool valid = (m < NN);
#pragma unroll
  for (int hi = 0; hi < 8; ++hi) {
#pragma unroll
    for (int r = 0; r < 4; ++r) {
      const int h = hi * 16 + lg * 4 + r;
      ob[h * NPAD] = valid ? f2bf(acc[hi][r]) : (unsigned short)0;
    }
  }
}

// ---------------- K2: H1 = relu(adj@XW1 + b1); gh1 += colsum; H1W2T = (H1@W2)^T ----------
__global__ __launch_bounds__(256) void k_h1(const float* __restrict__ adj,
                                            const unsigned short* __restrict__ XW1T,
                                            const unsigned short* __restrict__ W2T,
                                            const float* __restrict__ b1,
                                            unsigned short* __restrict__ H1W2T,
                                            float* __restrict__ gh) {
  // XCD-affine swizzle: all 6 blocks of batch b land on XCD b%8 (bijective, grid=1536)
  const int id  = blockIdx.x;
  const int xcd = id & 7, j = id >> 3;
  const int b   = (j / 6) * 8 + xcd;
  const int mt  = j % 6;
  const int wid = threadIdx.x >> 6;
  const int lane = threadIdx.x & 63;
  const int l15 = lane & 15, lg = lane >> 4;
  const int arowi  = mt * 64 + wid * 16 + l15;       // adj row (== output row group)
  const int arowld = arowi < NN ? arowi : NN - 1;
  const float* arow = adj + ((size_t)b * NN + arowld) * NN;
  const unsigned short* xw = XW1T + (size_t)b * NH * NPAD;

  // hoist adj row into regs (bf16)
  const bf16x8 bz = {0, 0, 0, 0, 0, 0, 0, 0};
  bf16x8 areg[12];
#pragma unroll
  for (int ks = 0; ks < 12; ++ks) {
    const int k0 = ks * 32 + lg * 8;
    areg[ks] = (k0 + 8 <= NN) ? cvt8(arow + k0) : bz;
  }

  const f32x4 fz = {0.f, 0.f, 0.f, 0.f};
  f32x4 acc[8];
#pragma unroll
  for (int i = 0; i < 8; ++i) acc[i] = fz;

#pragma unroll
  for (int ks = 0; ks < 12; ++ks) {
    const int k0 = ks * 32 + lg * 8;
    bf16x8 bf[8];
#pragma unroll
    for (int ni = 0; ni < 8; ++ni)
      bf[ni] = *(const bf16x8*)(xw + (ni * 16 + l15) * NPAD + k0);
#pragma unroll
    for (int ni = 0; ni < 8; ++ni)
      acc[ni] = __builtin_amdgcn_mfma_f32_16x16x32_bf16(areg[ks], bf[ni], acc[ni], 0, 0, 0);
  }

  // epilogue: bias + relu + row-mask; stash H1 (bf16) in wave-private LDS; gh1 col-sums
  __shared__ unsigned short h1s[4][16][NH + 8];      // pad stride -> conflict-free b128 reads
  float* ghb = gh + b * 256;
#pragma unroll
  for (int ni = 0; ni < 8; ++ni) {
    const int col = ni * 16 + l15;
    const float bias = b1[col];
    f32x4 v = acc[ni];
    float s = 0.f;
#pragma unroll
    for (int r = 0; r < 4; ++r) {
      const int orow = mt * 64 + wid * 16 + lg * 4 + r;
      float h = v[r] + bias;
      h = h > 0.f ? h : 0.f;
      if (orow >= NN) h = 0.f;
      h1s[wid][lg * 4 + r][col] = f2bf(h);
      s += h;
    }
    s += __shfl_xor(s, 16);
    s += __shfl_xor(s, 32);
    if (lg == 0) atomicAdd(&ghb[col], s);
  }
  __syncthreads();

  // second GEMM: (H1 16x128) @ (W2 128x128), K fully in-wave
  f32x4 acc2[8];
#pragma unroll
  for (int i = 0; i < 8; ++i) acc2[i] = fz;
#pragma unroll
  for (int ks = 0; ks < 4; ++ks) {
    const int k0 = ks * 32 + lg * 8;
    bf16x8 afrag = *(const bf16x8*)&h1s[wid][l15][k0];
#pragma unroll
    for (int ni = 0; ni < 8; ++ni) {
      bf16x8 bfrag = *(const bf16x8*)(W2T + (ni * 16 + l15) * NH + k0);
      acc2[ni] = __builtin_amdgcn_mfma_f32_16x16x32_bf16(afrag, bfrag, acc2[ni], 0, 0, 0);
    }
  }
  unsigned short* ob = H1W2T + (size_t)b * NH * NPAD;
#pragma unroll
  for (int ni = 0; ni < 8; ++ni) {
    const int h = ni * 16 + l15;
#pragma unroll
    for (int r = 0; r < 4; ++r) {
      const int m = mt * 64 + wid * 16 + lg * 4 + r;  // masked rows were zeroed -> stores 0
      ob[h * NPAD + m] = f2bf(acc2[ni][r]);
    }
  }
}

// ---------------- K3: H2 = relu(adj@H1W2 + b2) -> out f32; gh2 += colsum -----------------
__global__ __launch_bounds__(256) void k_h2(const float* __restrict__ adj,
                                            const unsigned short* __restrict__ H1W2T,
                                            const float* __restrict__ b2,
                                            float* __restrict__ out,
                                            float* __restrict__ gh) {
  const int id  = blockIdx.x;
  const int xcd = id & 7, j = id >> 3;
  const int b   = (j / 6) * 8 + xcd;
  const int mt  = j % 6;
  const int wid = threadIdx.x >> 6;
  const int lane = threadIdx.x & 63;
  const int l15 = lane & 15, lg = lane >> 4;
  const int arowi  = mt * 64 + wid * 16 + l15;
  const int arowld = arowi < NN ? arowi : NN - 1;
  const float* arow = adj + ((size_t)b * NN + arowld) * NN;
  const unsigned short* hw = H1W2T + (size_t)b * NH * NPAD;

  const bf16x8 bz = {0, 0, 0, 0, 0, 0, 0, 0};
  bf16x8 areg[12];
#pragma unroll
  for (int ks = 0; ks < 12; ++ks) {
    const int k0 = ks * 32 + lg * 8;
    areg[ks] = (k0 + 8 <= NN) ? cvt8(arow + k0) : bz;
  }

  const f32x4 fz = {0.f, 0.f, 0.f, 0.f};
  f32x4 acc[8];
#pragma unroll
  for (int i = 0; i < 8; ++i) acc[i] = fz;

#pragma unroll
  for (int ks = 0; ks < 12; ++ks) {
    const int k0 = ks * 32 + lg * 8;
    bf16x8 bf[8];
#pragma unroll
    for (int ni = 0; ni < 8; ++ni)
      bf[ni] = *(const bf16x8*)(hw + (ni * 16 + l15) * NPAD + k0);
#pragma unroll
    for (int ni = 0; ni < 8; ++ni)
      acc[ni] = __builtin_amdgcn_mfma_f32_16x16x32_bf16(areg[ks], bf[ni], acc[ni], 0, 0, 0);
  }

  float* ghb  = gh + b * 256 + 128;
  float* outb = out + (size_t)b * NN * NH;
#pragma unroll
  for (int ni = 0; ni < 8; ++ni) {
    const int col = ni * 16 + l15;
    const float bias = b2[col];
    f32x4 v = acc[ni];
    float s = 0.f;
#pragma unroll
    for (int r = 0; r < 4; ++r) {
      const int orow = mt * 64 + wid * 16 + lg * 4 + r;
      float h = v[r] + bias;
      h = h > 0.f ? h : 0.f;
      if (orow < NN) {
        outb[orow * NH + col] = h;
        s += h;
      }
    }
    s += __shfl_xor(s, 16);
    s += __shfl_xor(s, 32);
    if (lg == 0) atomicAdd(&ghb[col], s);
  }
}

extern "C" void kernel_launch(void* const* d_in, const int* in_sizes, int n_in,
                              void* d_out, int out_size, void* d_ws, size_t ws_size,
                              hipStream_t stream) {
  const float* x   = (const float*)d_in[0];
  const float* adj = (const float*)d_in[1];
  const float* W1  = (const float*)d_in[2];
  const float* b1  = (const float*)d_in[3];
  const float* W2  = (const float*)d_in[4];
  const float* b2  = (const float*)d_in[5];
  float* out = (float*)d_out;                         // h2 [256,360,128] then gh [256,256]
  float* gh  = out + (size_t)NB * NN * NH;

  char* ws = (char*)d_ws;
  // ws layout (bf16): XW1T [256][128][384] | H1W2T [256][128][384] | W1T [128][384] | W2T [128][128]
  unsigned short* XW1T  = (unsigned short*)ws;                          // 25,165,824 B
  unsigned short* H1W2T = (unsigned short*)(ws + 25165824);             // 25,165,824 B
  unsigned short* W1T   = (unsigned short*)(ws + 50331648);             //     98,304 B
  unsigned short* W2T   = (unsigned short*)(ws + 50331648 + 98304);     //     32,768 B

  k_prep<<<512, 256, 0, stream>>>(W1, W2, W1T, W2T, gh);
  k_xw1 <<<NB * 6, 256, 0, stream>>>(x, W1T, XW1T);
  k_h1  <<<NB * 6, 256, 0, stream>>>(adj, XW1T, W2T, b1, H1W2T, gh);
  k_h2  <<<NB * 6, 256, 0, stream>>>(adj, H1W2T, b2, out, gh);
}

// Round 3
// 150.451 us; speedup vs baseline: 2.0997x; 2.0711x over previous
//
#include <hip/hip_runtime.h>

#define NB 256   // batch
#define NN 360   // nodes
#define NF 360   // nfeat
#define NH 128   // nhid
#define NKS 12   // 12 k-slices of 32 cover padded 384
#define TILE_B 8192                 // bytes per tile: [128 rows][32 k] bf16
#define PANEL_B (NKS * TILE_B)      // 98304 B per batch panel

using bf16x8 = __attribute__((ext_vector_type(8))) short;
using f32x4  = __attribute__((ext_vector_type(4))) float;

static __device__ __forceinline__ unsigned short f2bf(float f) {
  union { float f; unsigned u; } v; v.f = f;
  unsigned r = v.u + 0x7FFFu + ((v.u >> 16) & 1u);  // RNE
  return (unsigned short)(r >> 16);
}

static __device__ __forceinline__ bf16x8 cvt8(const float* __restrict__ p) {
  float4 a = *(const float4*)p;
  float4 b = *(const float4*)(p + 4);
  bf16x8 r;
  r[0] = (short)f2bf(a.x); r[1] = (short)f2bf(a.y);
  r[2] = (short)f2bf(a.z); r[3] = (short)f2bf(a.w);
  r[4] = (short)f2bf(b.x); r[5] = (short)f2bf(b.y);
  r[6] = (short)f2bf(b.z); r[7] = (short)f2bf(b.w);
  return r;
}

// tile byte offset for logical (row n, k-within-tile j), XOR-swizzled
static __device__ __forceinline__ int toff(int n, int j) {
  return (n * 64 + j * 2) ^ ((n & 7) << 4);
}

// async global->LDS, 16B per lane: dst = uniform wave base, HW adds lane*16
static __device__ __forceinline__ void glds16(const void* src, void* dst) {
  __builtin_amdgcn_global_load_lds(
      (const __attribute__((address_space(1))) void*)src,
      (__attribute__((address_space(3))) void*)dst, 16, 0, 0);
}

// ---------------- K0: build swizzled kt-tiles of W1^T and W2^T --------------------------
__global__ void k_prep(const float* __restrict__ W1, const float* __restrict__ W2,
                       unsigned short* __restrict__ W1T, unsigned short* __restrict__ W2T) {
  const int t = blockIdx.x * 256 + threadIdx.x;     // 65536 = 12*4096 + 4*4096
  if (t < NKS * 4096) {
    const int ks = t >> 12, r = t & 4095;
    const int n = r >> 5, j = r & 31;               // n = hidden h, k = feat
    const int k = ks * 32 + j;
    const float v = (k < NF) ? W1[k * NH + n] : 0.f;
    *(unsigned short*)((char*)W1T + ks * TILE_B + toff(n, j)) = f2bf(v);
  } else {
    const int t2 = t - NKS * 4096;
    const int ks = t2 >> 12, r = t2 & 4095;
    const int n = r >> 5, j = r & 31;               // n = out hidden, k = in hidden
    const int k = ks * 32 + j;
    *(unsigned short*)((char*)W2T + ks * TILE_B + toff(n, j)) = f2bf(W2[k * NH + n]);
  }
}

// ---------------- K1: XW1T tiles[b][ks][h][m%32] = (x@W1)^T -----------------------------
__global__ __launch_bounds__(256) void k_xw1(const float* __restrict__ x,
                                             const unsigned short* __restrict__ W1T,
                                             unsigned short* __restrict__ XW1T) {
  const int id = blockIdx.x;
  const int xcd = id & 7, jj = id >> 3;
  const int b = (jj / 6) * 8 + xcd;
  const int mt = jj % 6;
  const int wid = threadIdx.x >> 6, lane = threadIdx.x & 63;
  const int l15 = lane & 15, lg = lane >> 4;
  const int m = mt * 64 + wid * 16 + l15;           // x row == output column
  const int mld = m < NN ? m : NN - 1;
  const float* xrow = x + ((size_t)b * NN + mld) * NF;

  const bf16x8 bz = {0, 0, 0, 0, 0, 0, 0, 0};
  bf16x8 breg[NKS];
#pragma unroll
  for (int ks = 0; ks < NKS; ++ks) {
    const int k0 = ks * 32 + lg * 8;
    breg[ks] = (k0 + 8 <= NF) ? cvt8(xrow + k0) : bz;
  }

  __shared__ __align__(16) char smem[3 * TILE_B];
  const char* pan = (const char*)W1T;
  const int stoff = wid * 2048 + (lane << 4);
  const int rdbase = (l15 * 64 + lg * 16) ^ ((l15 & 7) << 4);

  glds16(pan + stoff, smem + wid * 2048);
  glds16(pan + stoff + 1024, smem + wid * 2048 + 1024);

  const f32x4 fz = {0.f, 0.f, 0.f, 0.f};
  f32x4 acc[8];
#pragma unroll
  for (int i = 0; i < 8; ++i) acc[i] = fz;

#pragma unroll
  for (int ks = 0; ks < NKS; ++ks) {
    if (ks + 1 < NKS) {
      const char* src = pan + (ks + 1) * TILE_B + stoff;
      char* dst = smem + ((ks + 1) % 3) * TILE_B + wid * 2048;
      glds16(src, dst); glds16(src + 1024, dst + 1024);
    }
    __syncthreads();
    const char* sb = smem + (ks % 3) * TILE_B;
#pragma unroll
    for (int hi = 0; hi < 8; ++hi) {
      bf16x8 af = *(const bf16x8*)(sb + hi * 1024 + rdbase);
      acc[hi] = __builtin_amdgcn_mfma_f32_16x16x32_bf16(af, breg[ks], acc[hi], 0, 0, 0);
    }
  }

  char* ob = (char*)XW1T + (size_t)b * PANEL_B + (m >> 5) * TILE_B;
  const int j2 = (m & 31) * 2;
  const bool valid = (m < NN);
#pragma unroll
  for (int hi = 0; hi < 8; ++hi) {
#pragma unroll
    for (int r = 0; r < 4; ++r) {
      const int n = hi * 16 + lg * 4 + r;
      const unsigned short v = valid ? f2bf(acc[hi][r]) : (unsigned short)0;
      *(unsigned short*)(ob + (((n * 64 + j2) ^ ((n & 7) << 4)))) = v;
    }
  }
}

// ---------------- K2: H1 = relu(adj@XW1+b1); ghp1 partials; H1W2T tiles = (H1@W2)^T -----
__global__ __launch_bounds__(256) void k_h1(const float* __restrict__ adj,
                                            const unsigned short* __restrict__ XW1T,
                                            const unsigned short* __restrict__ W2T,
                                            const float* __restrict__ b1,
                                            unsigned short* __restrict__ H1W2T,
                                            float* __restrict__ ghp1) {
  const int id = blockIdx.x;
  const int xcd = id & 7, jj = id >> 3;
  const int b = (jj / 6) * 8 + xcd;
  const int mt = jj % 6;
  const int wid = threadIdx.x >> 6, lane = threadIdx.x & 63;
  const int l15 = lane & 15, lg = lane >> 4;
  const int arowi = mt * 64 + wid * 16 + l15;
  const int arowld = arowi < NN ? arowi : NN - 1;
  const float* arow = adj + ((size_t)b * NN + arowld) * NN;

  const bf16x8 bz = {0, 0, 0, 0, 0, 0, 0, 0};
  bf16x8 areg[NKS];
#pragma unroll
  for (int ks = 0; ks < NKS; ++ks) {
    const int k0 = ks * 32 + lg * 8;
    areg[ks] = (k0 + 8 <= NN) ? cvt8(arow + k0) : bz;
  }

  __shared__ __align__(16) char smem[3 * TILE_B];
  const char* pan = (const char*)XW1T + (size_t)b * PANEL_B;
  const int stoff = wid * 2048 + (lane << 4);
  const int rdbase = (l15 * 64 + lg * 16) ^ ((l15 & 7) << 4);

  glds16(pan + stoff, smem + wid * 2048);
  glds16(pan + stoff + 1024, smem + wid * 2048 + 1024);

  const f32x4 fz = {0.f, 0.f, 0.f, 0.f};
  f32x4 acc[8];
#pragma unroll
  for (int i = 0; i < 8; ++i) acc[i] = fz;

#pragma unroll
  for (int ks = 0; ks < NKS; ++ks) {
    if (ks + 1 < NKS) {
      const char* src = pan + (ks + 1) * TILE_B + stoff;
      char* dst = smem + ((ks + 1) % 3) * TILE_B + wid * 2048;
      glds16(src, dst); glds16(src + 1024, dst + 1024);
    }
    __syncthreads();
    const char* sb = smem + (ks % 3) * TILE_B;
#pragma unroll
    for (int ni = 0; ni < 8; ++ni) {
      bf16x8 bf = *(const bf16x8*)(sb + ni * 1024 + rdbase);
      acc[ni] = __builtin_amdgcn_mfma_f32_16x16x32_bf16(areg[ks], bf, acc[ni], 0, 0, 0);
    }
  }
  __syncthreads();                                  // before reusing smem for h1s/ghl

  unsigned short* h1s = (unsigned short*)smem;      // [4][16][136] = 17408 B
  float* ghl = (float*)(smem + 17408);              // [4][128]    =  2048 B
#pragma unroll
  for (int ni = 0; ni < 8; ++ni) {
    const int col = ni * 16 + l15;
    const float bias = b1[col];
    float s = 0.f;
#pragma unroll
    for (int r = 0; r < 4; ++r) {
      const int orow = mt * 64 + wid * 16 + lg * 4 + r;
      float h = acc[ni][r] + bias;
      h = h > 0.f ? h : 0.f;
      if (orow >= NN) h = 0.f;
      h1s[(wid * 16 + lg * 4 + r) * 136 + col] = f2bf(h);
      s += h;
    }
    s += __shfl_xor(s, 16);
    s += __shfl_xor(s, 32);
    if (lg == 0) ghl[wid * 128 + col] = s;
  }
  __syncthreads();
  if (threadIdx.x < 128) {
    const int c = threadIdx.x;
    ghp1[(b * 6 + mt) * 128 + c] = ghl[c] + ghl[128 + c] + ghl[256 + c] + ghl[384 + c];
  }

  // GEMM2: (H1 16x128) @ W2, K in-wave; W2T kt-tiles direct from global (L1-resident)
  f32x4 acc2[8];
#pragma unroll
  for (int i = 0; i < 8; ++i) acc2[i] = fz;
  const char* w2 = (const char*)W2T;
#pragma unroll
  for (int ks = 0; ks < 4; ++ks) {
    const int k0 = ks * 32 + lg * 8;
    bf16x8 af = *(const bf16x8*)&h1s[(wid * 16 + l15) * 136 + k0];
#pragma unroll
    for (int ni = 0; ni < 8; ++ni) {
      bf16x8 bf = *(const bf16x8*)(w2 + ks * TILE_B + ni * 1024 + rdbase);
      acc2[ni] = __builtin_amdgcn_mfma_f32_16x16x32_bf16(af, bf, acc2[ni], 0, 0, 0);
    }
  }
  char* ob = (char*)H1W2T + (size_t)b * PANEL_B;
#pragma unroll
  for (int ni = 0; ni < 8; ++ni) {
    const int n = ni * 16 + l15;
    const int sw = (n & 7) << 4;
#pragma unroll
    for (int r = 0; r < 4; ++r) {
      const int m = mt * 64 + wid * 16 + lg * 4 + r;  // masked rows already zero
      *(unsigned short*)(ob + (m >> 5) * TILE_B + ((n * 64 + (m & 31) * 2) ^ sw)) =
          f2bf(acc2[ni][r]);
    }
  }
}

// ---------------- K3: H2 = relu(adj@H1W2 + b2) -> out f32; ghp2 partials ----------------
__global__ __launch_bounds__(256) void k_h2(const float* __restrict__ adj,
                                            const unsigned short* __restrict__ H1W2T,
                                            const float* __restrict__ b2,
                                            float* __restrict__ out,
                                            float* __restrict__ ghp2) {
  const int id = blockIdx.x;
  const int xcd = id & 7, jj = id >> 3;
  const int b = (jj / 6) * 8 + xcd;
  const int mt = jj % 6;
  const int wid = threadIdx.x >> 6, lane = threadIdx.x & 63;
  const int l15 = lane & 15, lg = lane >> 4;
  const int arowi = mt * 64 + wid * 16 + l15;
  const int arowld = arowi < NN ? arowi : NN - 1;
  const float* arow = adj + ((size_t)b * NN + arowld) * NN;

  const bf16x8 bz = {0, 0, 0, 0, 0, 0, 0, 0};
  bf16x8 areg[NKS];
#pragma unroll
  for (int ks = 0; ks < NKS; ++ks) {
    const int k0 = ks * 32 + lg * 8;
    areg[ks] = (k0 + 8 <= NN) ? cvt8(arow + k0) : bz;
  }

  __shared__ __align__(16) char smem[3 * TILE_B];
  const char* pan = (const char*)H1W2T + (size_t)b * PANEL_B;
  const int stoff = wid * 2048 + (lane << 4);
  const int rdbase = (l15 * 64 + lg * 16) ^ ((l15 & 7) << 4);

  glds16(pan + stoff, smem + wid * 2048);
  glds16(pan + stoff + 1024, smem + wid * 2048 + 1024);

  const f32x4 fz = {0.f, 0.f, 0.f, 0.f};
  f32x4 acc[8];
#pragma unroll
  for (int i = 0; i < 8; ++i) acc[i] = fz;

#pragma unroll
  for (int ks = 0; ks < NKS; ++ks) {
    if (ks + 1 < NKS) {
      const char* src = pan + (ks + 1) * TILE_B + stoff;
      char* dst = smem + ((ks + 1) % 3) * TILE_B + wid * 2048;
      glds16(src, dst); glds16(src + 1024, dst + 1024);
    }
    __syncthreads();
    const char* sb = smem + (ks % 3) * TILE_B;
#pragma unroll
    for (int ni = 0; ni < 8; ++ni) {
      bf16x8 bf = *(const bf16x8*)(sb + ni * 1024 + rdbase);
      acc[ni] = __builtin_amdgcn_mfma_f32_16x16x32_bf16(areg[ks], bf, acc[ni], 0, 0, 0);
    }
  }
  __syncthreads();                                  // before reusing smem for ghl

  float* ghl = (float*)smem;                        // [4][128]
  float* outb = out + (size_t)b * NN * NH;
#pragma unroll
  for (int ni = 0; ni < 8; ++ni) {
    const int col = ni * 16 + l15;
    const float bias = b2[col];
    float s = 0.f;
#pragma unroll
    for (int r = 0; r < 4; ++r) {
      const int orow = mt * 64 + wid * 16 + lg * 4 + r;
      float h = acc[ni][r] + bias;
      h = h > 0.f ? h : 0.f;
      if (orow < NN) {
        outb[orow * NH + col] = h;
        s += h;
      }
    }
    s += __shfl_xor(s, 16);
    s += __shfl_xor(s, 32);
    if (lg == 0) ghl[wid * 128 + col] = s;
  }
  __syncthreads();
  if (threadIdx.x < 128) {
    const int c = threadIdx.x;
    ghp2[(b * 6 + mt) * 128 + c] = ghl[c] + ghl[128 + c] + ghl[256 + c] + ghl[384 + c];
  }
}

// ---------------- K4: gh[b] = concat(sum_mt ghp1, sum_mt ghp2) --------------------------
__global__ void k_ghsum(const float* __restrict__ ghp1, const float* __restrict__ ghp2,
                        float* __restrict__ gh) {
  const int b = blockIdx.x, c = threadIdx.x;
  const float* src = (c < 128) ? (ghp1 + b * 768 + c) : (ghp2 + b * 768 + (c - 128));
  float s = 0.f;
#pragma unroll
  for (int mt = 0; mt < 6; ++mt) s += src[mt * 128];
  gh[b * 256 + c] = s;
}

extern "C" void kernel_launch(void* const* d_in, const int* in_sizes, int n_in,
                              void* d_out, int out_size, void* d_ws, size_t ws_size,
                              hipStream_t stream) {
  const float* x   = (const float*)d_in[0];
  const float* adj = (const float*)d_in[1];
  const float* W1  = (const float*)d_in[2];
  const float* b1  = (const float*)d_in[3];
  const float* W2  = (const float*)d_in[4];
  const float* b2  = (const float*)d_in[5];
  float* out = (float*)d_out;                       // h2 [256,360,128] then gh [256,256]
  float* gh  = out + (size_t)NB * NN * NH;

  char* ws = (char*)d_ws;
  unsigned short* XW1T  = (unsigned short*)ws;                  // 25,165,824 B
  unsigned short* H1W2T = (unsigned short*)(ws + 25165824);     // 25,165,824 B
  unsigned short* W1T   = (unsigned short*)(ws + 50331648);     //     98,304 B
  unsigned short* W2T   = (unsigned short*)(ws + 50429952);     //     32,768 B
  float*          ghp1  = (float*)(ws + 50462720);              //    786,432 B
  float*          ghp2  = (float*)(ws + 51249152);              //    786,432 B

  k_prep <<<256, 256, 0, stream>>>(W1, W2, W1T, W2T);
  k_xw1  <<<NB * 6, 256, 0, stream>>>(x, W1T, XW1T);
  k_h1   <<<NB * 6, 256, 0, stream>>>(adj, XW1T, W2T, b1, H1W2T, ghp1);
  k_h2   <<<NB * 6, 256, 0, stream>>>(adj, H1W2T, b2, out, ghp2);
  k_ghsum<<<NB, 256, 0, stream>>>(ghp1, ghp2, gh);
}

// Round 4
// 132.469 us; speedup vs baseline: 2.3847x; 1.1357x over previous
//
#include <hip/hip_runtime.h>

#define NB 256   // batch
#define NN 360   // nodes
#define NF 360   // nfeat
#define NH 128   // nhid
#define NKS 12   // 12 k-slices of 32 cover padded 384
#define TILE_B 8192                 // bytes per tile: [128 rows][32 k] bf16, fragment-linear
#define PANEL_B (NKS * TILE_B)      // 98304 B per batch panel

using bf16x8 = __attribute__((ext_vector_type(8))) short;
using f32x4  = __attribute__((ext_vector_type(4))) float;

static __device__ __forceinline__ unsigned short f2bf(float f) {
  union { float f; unsigned u; } v; v.f = f;
  unsigned r = v.u + 0x7FFFu + ((v.u >> 16) & 1u);  // RNE
  return (unsigned short)(r >> 16);
}

static __device__ __forceinline__ bf16x8 cvt8(const float* __restrict__ p) {
  float4 a = *(const float4*)p;
  float4 b = *(const float4*)(p + 4);
  bf16x8 r;
  r[0] = (short)f2bf(a.x); r[1] = (short)f2bf(a.y);
  r[2] = (short)f2bf(a.z); r[3] = (short)f2bf(a.w);
  r[4] = (short)f2bf(b.x); r[5] = (short)f2bf(b.y);
  r[6] = (short)f2bf(b.z); r[7] = (short)f2bf(b.w);
  return r;
}

// fragment-linear tile offset for logical (row n in 0..127, k j in 0..31):
// reader lane (lg*16+l15) gets its bf16x8 at ni*1024 + lane*16 (contiguous wave read)
static __device__ __forceinline__ int toff(int n, int j) {
  return ((n >> 4) << 10) + ((j >> 3) << 8) + ((n & 15) << 4) + ((j & 7) << 1);
}

// async global->LDS, 16B per lane: dst = uniform wave base, HW adds lane*16
static __device__ __forceinline__ void glds16(const void* src, void* dst) {
  __builtin_amdgcn_global_load_lds(
      (const __attribute__((address_space(1))) void*)src,
      (__attribute__((address_space(3))) void*)dst, 16, 0, 0);
}

// ---------------- K0: build fragment-linear kt-tiles of W1^T and W2^T -------------------
__global__ void k_prep(const float* __restrict__ W1, const float* __restrict__ W2,
                       unsigned short* __restrict__ W1T, unsigned short* __restrict__ W2T) {
  const int t = blockIdx.x * 256 + threadIdx.x;     // 65536 = 12*4096 + 4*4096
  if (t < NKS * 4096) {
    const int ks = t >> 12, r = t & 4095;
    const int n = r >> 5, j = r & 31;               // n = hidden h, k = feat
    const int k = ks * 32 + j;
    const float v = (k < NF) ? W1[k * NH + n] : 0.f;
    *(unsigned short*)((char*)W1T + ks * TILE_B + toff(n, j)) = f2bf(v);
  } else {
    const int t2 = t - NKS * 4096;
    const int ks = t2 >> 12, r = t2 & 4095;
    const int n = r >> 5, j = r & 31;               // n = out hidden, k = in hidden
    const int k = ks * 32 + j;
    *(unsigned short*)((char*)W2T + ks * TILE_B + toff(n, j)) = f2bf(W2[k * NH + n]);
  }
}

// pipelined stage+compute main loop (shared shape for the 3 GEMM kernels):
//   prologue: stage t0,t1. iter ks: wait vmcnt(2) [t(ks) done, t(ks+1) in flight],
//   s_barrier, issue t(ks+2), compute t(ks). Last iter waits vmcnt(0).
#define MAIN_LOOP(OPA_EXPR)                                                        \
  glds16(pan + stoff, smem + wid * 2048);                                          \
  glds16(pan + stoff + 1024, smem + wid * 2048 + 1024);                            \
  glds16(pan + TILE_B + stoff, smem + TILE_B + wid * 2048);                        \
  glds16(pan + TILE_B + stoff + 1024, smem + TILE_B + wid * 2048 + 1024);          \
  _Pragma("unroll")                                                                \
  for (int ks = 0; ks < NKS; ++ks) {                                               \
    if (ks < NKS - 1) asm volatile("s_waitcnt vmcnt(2)" ::: "memory");             \
    else              asm volatile("s_waitcnt vmcnt(0)" ::: "memory");             \
    __builtin_amdgcn_s_barrier();                                                  \
    __builtin_amdgcn_sched_barrier(0);                                             \
    if (ks + 2 < NKS) {                                                            \
      const char* src = pan + (ks + 2) * TILE_B + stoff;                           \
      char* dst = smem + ((ks + 2) % 3) * TILE_B + wid * 2048;                     \
      glds16(src, dst); glds16(src + 1024, dst + 1024);                            \
    }                                                                              \
    __builtin_amdgcn_sched_barrier(0);                                             \
    const char* sb = smem + (ks % 3) * TILE_B;                                     \
    _Pragma("unroll")                                                              \
    for (int ni = 0; ni < 8; ++ni) {                                               \
      bf16x8 bfv = *(const bf16x8*)(sb + ni * 1024 + (lane << 4));                 \
      acc[ni] = __builtin_amdgcn_mfma_f32_16x16x32_bf16((OPA_EXPR), bfv, acc[ni],  \
                                                        0, 0, 0);                  \
    }                                                                              \
  }

// ---------------- K1: XW1T tiles = (x@W1)^T ---------------------------------------------
__global__ __launch_bounds__(256) void k_xw1(const float* __restrict__ x,
                                             const unsigned short* __restrict__ W1T,
                                             unsigned short* __restrict__ XW1T) {
  const int id = blockIdx.x;
  const int xcd = id & 7, jj = id >> 3;
  const int b = (jj / 6) * 8 + xcd;
  const int mt = jj % 6;
  const int wid = threadIdx.x >> 6, lane = threadIdx.x & 63;
  const int l15 = lane & 15, lg = lane >> 4;
  const int m = mt * 64 + wid * 16 + l15;           // x row == output column
  const int mld = m < NN ? m : NN - 1;
  const float* xrow = x + ((size_t)b * NN + mld) * NF;

  const bf16x8 bz = {0, 0, 0, 0, 0, 0, 0, 0};
  bf16x8 areg[NKS];                                 // per-lane x row (B-operand here)
#pragma unroll
  for (int ks = 0; ks < NKS; ++ks) {
    const int k0 = ks * 32 + lg * 8;
    areg[ks] = (k0 + 8 <= NF) ? cvt8(xrow + k0) : bz;
  }

  __shared__ __align__(16) char smem[3 * TILE_B];
  const char* pan = (const char*)W1T;
  const int stoff = wid * 2048 + (lane << 4);

  const f32x4 fz = {0.f, 0.f, 0.f, 0.f};
  f32x4 acc[8];
#pragma unroll
  for (int i = 0; i < 8; ++i) acc[i] = fz;

  // note operand order: A = W1T fragment (rows=h), B = x row fragment
  bf16x8 bfv_dummy;
  (void)bfv_dummy;
  glds16(pan + stoff, smem + wid * 2048);
  glds16(pan + stoff + 1024, smem + wid * 2048 + 1024);
  glds16(pan + TILE_B + stoff, smem + TILE_B + wid * 2048);
  glds16(pan + TILE_B + stoff + 1024, smem + TILE_B + wid * 2048 + 1024);
#pragma unroll
  for (int ks = 0; ks < NKS; ++ks) {
    if (ks < NKS - 1) asm volatile("s_waitcnt vmcnt(2)" ::: "memory");
    else              asm volatile("s_waitcnt vmcnt(0)" ::: "memory");
    __builtin_amdgcn_s_barrier();
    __builtin_amdgcn_sched_barrier(0);
    if (ks + 2 < NKS) {
      const char* src = pan + (ks + 2) * TILE_B + stoff;
      char* dst = smem + ((ks + 2) % 3) * TILE_B + wid * 2048;
      glds16(src, dst); glds16(src + 1024, dst + 1024);
    }
    __builtin_amdgcn_sched_barrier(0);
    const char* sb = smem + (ks % 3) * TILE_B;
#pragma unroll
    for (int hi = 0; hi < 8; ++hi) {
      bf16x8 af = *(const bf16x8*)(sb + hi * 1024 + (lane << 4));
      acc[hi] = __builtin_amdgcn_mfma_f32_16x16x32_bf16(af, areg[ks], acc[hi], 0, 0, 0);
    }
  }

  // store fragment-linear: element (n=h, m): tile m>>5, offset toff(n, m&31)
  char* ob = (char*)XW1T + (size_t)b * PANEL_B + (m >> 5) * TILE_B;
  const int jm = m & 31;
  const int jadd = (((jm >> 3) << 8)) + ((jm & 7) << 1);
  const bool valid = (m < NN);
#pragma unroll
  for (int hi = 0; hi < 8; ++hi) {
#pragma unroll
    for (int r = 0; r < 4; ++r) {
      const unsigned short v = valid ? f2bf(acc[hi][r]) : (unsigned short)0;
      *(unsigned short*)(ob + hi * 1024 + jadd + ((lg * 4 + r) << 4)) = v;
    }
  }
}

// ---------------- K2: H1 = relu(adj@XW1+b1); ghp1 partials; H1W2T tiles = (H1@W2)^T -----
__global__ __launch_bounds__(256) void k_h1(const float* __restrict__ adj,
                                            const unsigned short* __restrict__ XW1T,
                                            const unsigned short* __restrict__ W2T,
                                            const float* __restrict__ b1,
                                            unsigned short* __restrict__ H1W2T,
                                            float* __restrict__ ghp1) {
  const int id = blockIdx.x;
  const int xcd = id & 7, jj = id >> 3;
  const int b = (jj / 6) * 8 + xcd;
  const int mt = jj % 6;
  const int wid = threadIdx.x >> 6, lane = threadIdx.x & 63;
  const int l15 = lane & 15, lg = lane >> 4;
  const int arowi = mt * 64 + wid * 16 + l15;
  const int arowld = arowi < NN ? arowi : NN - 1;
  const float* arow = adj + ((size_t)b * NN + arowld) * NN;

  const bf16x8 bz = {0, 0, 0, 0, 0, 0, 0, 0};
  bf16x8 areg[NKS];
#pragma unroll
  for (int ks = 0; ks < NKS; ++ks) {
    const int k0 = ks * 32 + lg * 8;
    areg[ks] = (k0 + 8 <= NN) ? cvt8(arow + k0) : bz;
  }

  __shared__ __align__(16) char smem[3 * TILE_B];
  const char* pan = (const char*)XW1T + (size_t)b * PANEL_B;
  const int stoff = wid * 2048 + (lane << 4);

  const f32x4 fz = {0.f, 0.f, 0.f, 0.f};
  f32x4 acc[8];
#pragma unroll
  for (int i = 0; i < 8; ++i) acc[i] = fz;

  MAIN_LOOP(areg[ks])

  __syncthreads();                                  // before reusing smem for h1s/ghl

  unsigned short* h1s = (unsigned short*)smem;      // [64][136] = 17408 B
  float* ghl = (float*)(smem + 17408);              // [4][128]  =  2048 B
#pragma unroll
  for (int ni = 0; ni < 8; ++ni) {
    const int col = ni * 16 + l15;
    const float bias = b1[col];
    float s = 0.f;
#pragma unroll
    for (int r = 0; r < 4; ++r) {
      const int orow = mt * 64 + wid * 16 + lg * 4 + r;
      float h = acc[ni][r] + bias;
      h = h > 0.f ? h : 0.f;
      if (orow >= NN) h = 0.f;
      h1s[(wid * 16 + lg * 4 + r) * 136 + col] = f2bf(h);
      s += h;
    }
    s += __shfl_xor(s, 16);
    s += __shfl_xor(s, 32);
    if (lg == 0) ghl[wid * 128 + col] = s;
  }
  __syncthreads();
  if (threadIdx.x < 128) {
    const int c = threadIdx.x;
    ghp1[(b * 6 + mt) * 128 + c] = ghl[c] + ghl[128 + c] + ghl[256 + c] + ghl[384 + c];
  }

  // GEMM2: (H1 16x128) @ W2, K in-wave; W2T tiles direct from global (L1/L2-resident)
  f32x4 acc2[8];
#pragma unroll
  for (int i = 0; i < 8; ++i) acc2[i] = fz;
  const char* w2 = (const char*)W2T;
#pragma unroll
  for (int ks = 0; ks < 4; ++ks) {
    const int k0 = ks * 32 + lg * 8;
    bf16x8 af = *(const bf16x8*)&h1s[(wid * 16 + l15) * 136 + k0];
#pragma unroll
    for (int ni = 0; ni < 8; ++ni) {
      bf16x8 bf = *(const bf16x8*)(w2 + ks * TILE_B + ni * 1024 + (lane << 4));
      acc2[ni] = __builtin_amdgcn_mfma_f32_16x16x32_bf16(af, bf, acc2[ni], 0, 0, 0);
    }
  }
  char* ob = (char*)H1W2T + (size_t)b * PANEL_B;
#pragma unroll
  for (int ni = 0; ni < 8; ++ni) {
#pragma unroll
    for (int r = 0; r < 4; ++r) {
      const int m = mt * 64 + wid * 16 + lg * 4 + r;  // masked rows already zero
      const int j = m & 31;
      *(unsigned short*)(ob + (m >> 5) * TILE_B + ni * 1024 + ((j >> 3) << 8) +
                         (l15 << 4) + ((j & 7) << 1)) = f2bf(acc2[ni][r]);
    }
  }
}

// ---------------- K3: H2 = relu(adj@H1W2 + b2) -> out f32; ghp2 partials ----------------
__global__ __launch_bounds__(256) void k_h2(const float* __restrict__ adj,
                                            const unsigned short* __restrict__ H1W2T,
                                            const float* __restrict__ b2,
                                            float* __restrict__ out,
                                            float* __restrict__ ghp2) {
  const int id = blockIdx.x;
  const int xcd = id & 7, jj = id >> 3;
  const int b = (jj / 6) * 8 + xcd;
  const int mt = jj % 6;
  const int wid = threadIdx.x >> 6, lane = threadIdx.x & 63;
  const int l15 = lane & 15, lg = lane >> 4;
  const int arowi = mt * 64 + wid * 16 + l15;
  const int arowld = arowi < NN ? arowi : NN - 1;
  const float* arow = adj + ((size_t)b * NN + arowld) * NN;

  const bf16x8 bz = {0, 0, 0, 0, 0, 0, 0, 0};
  bf16x8 areg[NKS];
#pragma unroll
  for (int ks = 0; ks < NKS; ++ks) {
    const int k0 = ks * 32 + lg * 8;
    areg[ks] = (k0 + 8 <= NN) ? cvt8(arow + k0) : bz;
  }

  __shared__ __align__(16) char smem[3 * TILE_B];
  const char* pan = (const char*)H1W2T + (size_t)b * PANEL_B;
  const int stoff = wid * 2048 + (lane << 4);

  const f32x4 fz = {0.f, 0.f, 0.f, 0.f};
  f32x4 acc[8];
#pragma unroll
  for (int i = 0; i < 8; ++i) acc[i] = fz;

  MAIN_LOOP(areg[ks])

  __syncthreads();                                  // before reusing smem for ghl

  float* ghl = (float*)smem;                        // [4][128]
  float* outb = out + (size_t)b * NN * NH;
#pragma unroll
  for (int ni = 0; ni < 8; ++ni) {
    const int col = ni * 16 + l15;
    const float bias = b2[col];
    float s = 0.f;
#pragma unroll
    for (int r = 0; r < 4; ++r) {
      const int orow = mt * 64 + wid * 16 + lg * 4 + r;
      float h = acc[ni][r] + bias;
      h = h > 0.f ? h : 0.f;
      if (orow < NN) {
        outb[orow * NH + col] = h;
        s += h;
      }
    }
    s += __shfl_xor(s, 16);
    s += __shfl_xor(s, 32);
    if (lg == 0) ghl[wid * 128 + col] = s;
  }
  __syncthreads();
  if (threadIdx.x < 128) {
    const int c = threadIdx.x;
    ghp2[(b * 6 + mt) * 128 + c] = ghl[c] + ghl[128 + c] + ghl[256 + c] + ghl[384 + c];
  }
}

// ---------------- K4: gh[b] = concat(sum_mt ghp1, sum_mt ghp2) --------------------------
__global__ void k_ghsum(const float* __restrict__ ghp1, const float* __restrict__ ghp2,
                        float* __restrict__ gh) {
  const int b = blockIdx.x, c = threadIdx.x;
  const float* src = (c < 128) ? (ghp1 + b * 768 + c) : (ghp2 + b * 768 + (c - 128));
  float s = 0.f;
#pragma unroll
  for (int mt = 0; mt < 6; ++mt) s += src[mt * 128];
  gh[b * 256 + c] = s;
}

extern "C" void kernel_launch(void* const* d_in, const int* in_sizes, int n_in,
                              void* d_out, int out_size, void* d_ws, size_t ws_size,
                              hipStream_t stream) {
  const float* x   = (const float*)d_in[0];
  const float* adj = (const float*)d_in[1];
  const float* W1  = (const float*)d_in[2];
  const float* b1  = (const float*)d_in[3];
  const float* W2  = (const float*)d_in[4];
  const float* b2  = (const float*)d_in[5];
  float* out = (float*)d_out;                       // h2 [256,360,128] then gh [256,256]
  float* gh  = out + (size_t)NB * NN * NH;

  char* ws = (char*)d_ws;
  unsigned short* XW1T  = (unsigned short*)ws;                  // 25,165,824 B
  unsigned short* H1W2T = (unsigned short*)(ws + 25165824);     // 25,165,824 B
  unsigned short* W1T   = (unsigned short*)(ws + 50331648);     //     98,304 B
  unsigned short* W2T   = (unsigned short*)(ws + 50429952);     //     32,768 B
  float*          ghp1  = (float*)(ws + 50462720);              //    786,432 B
  float*          ghp2  = (float*)(ws + 51249152);              //    786,432 B

  k_prep <<<256, 256, 0, stream>>>(W1, W2, W1T, W2T);
  k_xw1  <<<NB * 6, 256, 0, stream>>>(x, W1T, XW1T);
  k_h1   <<<NB * 6, 256, 0, stream>>>(adj, XW1T, W2T, b1, H1W2T, ghp1);
  k_h2   <<<NB * 6, 256, 0, stream>>>(adj, H1W2T, b2, out, ghp2);
  k_ghsum<<<NB, 256, 0, stream>>>(ghp1, ghp2, gh);
}

// Round 5
// 121.931 us; speedup vs baseline: 2.5908x; 1.0864x over previous
//
#include <hip/hip_runtime.h>

#define NB 256
#define NN 360
#define NF 360
#define NH 128
#define NKS 12   // 12 k-slices of 32 cover padded 384

using bf16x8 = __attribute__((ext_vector_type(8))) short;
using f32x4  = __attribute__((ext_vector_type(4))) float;

static __device__ __forceinline__ unsigned short f2bf(float f) {
  union { float f; unsigned u; } v; v.f = f;
  unsigned r = v.u + 0x7FFFu + ((v.u >> 16) & 1u);  // RNE
  return (unsigned short)(r >> 16);
}

static __device__ __forceinline__ bf16x8 pack8(float4 a, float4 b) {
  bf16x8 r;
  r[0] = (short)f2bf(a.x); r[1] = (short)f2bf(a.y);
  r[2] = (short)f2bf(a.z); r[3] = (short)f2bf(a.w);
  r[4] = (short)f2bf(b.x); r[5] = (short)f2bf(b.y);
  r[6] = (short)f2bf(b.z); r[7] = (short)f2bf(b.w);
  return r;
}

// fragment-linear (toff) tile offset for weight tiles in ws: reader lane gets its
// bf16x8 for (row ni*16+l15, k lg*8..) at ni*1024 + lane*16
static __device__ __forceinline__ int toff(int n, int j) {
  return ((n >> 4) << 10) + ((j >> 3) << 8) + ((n & 15) << 4) + ((j & 7) << 1);
}

// ---------------- K0: build fragment-linear kt-tiles of W1^T and W2^T -------------------
__global__ void k_prep(const float* __restrict__ W1, const float* __restrict__ W2,
                       unsigned short* __restrict__ W1T, unsigned short* __restrict__ W2T) {
  const int t = blockIdx.x * 256 + threadIdx.x;     // 65536 = 12*4096 + 4*4096
  if (t < NKS * 4096) {
    const int ks = t >> 12, r = t & 4095;
    const int n = r >> 5, j = r & 31;               // n = hidden h, k = feat
    const int k = ks * 32 + j;
    const float v = (k < NF) ? W1[k * NH + n] : 0.f;
    *(unsigned short*)((char*)W1T + ks * 8192 + toff(n, j)) = f2bf(v);
  } else {
    const int t2 = t - NKS * 4096;
    const int ks = t2 >> 12, r = t2 & 4095;
    const int n = r >> 5, j = r & 31;               // n = out hidden, k = in hidden
    const int k = ks * 32 + j;
    *(unsigned short*)((char*)W2T + ks * 8192 + toff(n, j)) = f2bf(W2[k * NH + n]);
  }
}

// ---------------- fused per-batch kernel ------------------------------------------------
// LDS: panel[12 tiles][8KB] (phase A: XW1, phase B2+: H1W2) | h1s[12 waves][16][136] | ghl[12][128]
// panel chunk layout: tile ks holds [128 rows][32 cols]; 16B chunk (rowgrp ni, l15_r, lg_r)
// at ni*1024 + F(l15_r,lg_r)*... F byte = (l15&3)*256 + (lg>>1)*128 + (l15>>2)*32 + (lg&1)*16
__global__ __launch_bounds__(768, 1) void k_fused(
    const float* __restrict__ x, const float* __restrict__ adj,
    const unsigned short* __restrict__ W1T, const unsigned short* __restrict__ W2T,
    const float* __restrict__ b1, const float* __restrict__ b2,
    float* __restrict__ out, float* __restrict__ gh) {
  const int b = blockIdx.x;
  const int tid = threadIdx.x;
  const int wid = tid >> 6, lane = tid & 63, l15 = lane & 15, lg = lane >> 4;
  extern __shared__ char smem[];
  char* panel = smem;                                             // 98304 B
  unsigned short* h1s = (unsigned short*)(smem + 98304) + wid * 2176;  // 4352 B/wave
  float* ghl = (float*)(smem + 98304 + 52224);                    // 6144 B

  const int fb = (l15 & 3) * 256 + (lg >> 1) * 128 + (l15 >> 2) * 32 + (lg & 1) * 16;
  const int kofs = lg * 8;
  const f32x4 fz = {0.f, 0.f, 0.f, 0.f};
  const bf16x8 bz = {0, 0, 0, 0, 0, 0, 0, 0};

  float b1v[8], b2v[8];
#pragma unroll
  for (int ni = 0; ni < 8; ++ni) {
    b1v[ni] = b1[ni * 16 + l15];
    b2v[ni] = b2[ni * 16 + l15];
  }

  f32x4 acc[2][8];
  float4 pa[2], pb[2];

  // =============== PHASE A: panel = (x@W1)^T =================
  const float* xr[2];
#pragma unroll
  for (int t = 0; t < 2; ++t) {
    const int m = (wid * 2 + t) * 16 + l15;
    const int mld = m < NN ? m : NN - 1;
    xr[t] = x + ((size_t)b * NN + mld) * NF;
  }
#pragma unroll
  for (int t = 0; t < 2; ++t) {
    pa[t] = *(const float4*)(xr[t] + kofs);
    pb[t] = *(const float4*)(xr[t] + kofs + 4);
  }
#pragma unroll
  for (int i = 0; i < 2; ++i)
#pragma unroll
    for (int j = 0; j < 8; ++j) acc[i][j] = fz;

#pragma unroll
  for (int ks = 0; ks < NKS; ++ks) {
    const bool kvalid = (ks * 32 + kofs + 8) <= NF;
    bf16x8 br0 = kvalid ? pack8(pa[0], pb[0]) : bz;
    bf16x8 br1 = kvalid ? pack8(pa[1], pb[1]) : bz;
    if (ks < NKS - 1) {
      int kk = (ks + 1) * 32 + kofs; kk = kk < 352 ? kk : 352;
#pragma unroll
      for (int t = 0; t < 2; ++t) {
        pa[t] = *(const float4*)(xr[t] + kk);
        pb[t] = *(const float4*)(xr[t] + kk + 4);
      }
    }
#pragma unroll
    for (int hi = 0; hi < 8; ++hi) {
      bf16x8 af = *(const bf16x8*)(W1T + ks * 4096 + hi * 512 + lane * 8);
      acc[0][hi] = __builtin_amdgcn_mfma_f32_16x16x32_bf16(af, br0, acc[0][hi], 0, 0, 0);
      acc[1][hi] = __builtin_amdgcn_mfma_f32_16x16x32_bf16(af, br1, acc[1][hi], 0, 0, 0);
    }
  }
  // write panel1: lane holds (h = hi*16+lg*4+r, m = (wid*2+t)*16+l15); per-instr 128B contiguous
#pragma unroll
  for (int t = 0; t < 2; ++t) {
    const int m = (wid * 2 + t) * 16 + l15;
    const bool valid = m < NN;
    char* base = panel + wid * 8192 + t * 128 + lg * 32 + (l15 >> 3) * 16 + (l15 & 7) * 2;
#pragma unroll
    for (int hi = 0; hi < 8; ++hi)
#pragma unroll
      for (int r = 0; r < 4; ++r)
        *(unsigned short*)(base + hi * 1024 + r * 256) =
            valid ? f2bf(acc[t][hi][r]) : (unsigned short)0;
  }
  __syncthreads();   // #1: panel1 (XW1) ready

  // =============== PHASE B: H1 = relu(adj@XW1+b1); H1W2 packed to regs =================
  const float* ar[2];
#pragma unroll
  for (int t = 0; t < 2; ++t) {
    const int n = (wid * 2 + t) * 16 + l15;
    const int nld = n < NN ? n : NN - 1;
    ar[t] = adj + ((size_t)b * NN + nld) * NN;
  }
#pragma unroll
  for (int t = 0; t < 2; ++t) {
    pa[t] = *(const float4*)(ar[t] + kofs);
    pb[t] = *(const float4*)(ar[t] + kofs + 4);
  }
#pragma unroll
  for (int i = 0; i < 2; ++i)
#pragma unroll
    for (int j = 0; j < 8; ++j) acc[i][j] = fz;

#pragma unroll
  for (int ks = 0; ks < NKS; ++ks) {
    const bool kvalid = (ks * 32 + kofs + 8) <= NN;
    bf16x8 br0 = kvalid ? pack8(pa[0], pb[0]) : bz;
    bf16x8 br1 = kvalid ? pack8(pa[1], pb[1]) : bz;
    if (ks < NKS - 1) {
      int kk = (ks + 1) * 32 + kofs; kk = kk < 352 ? kk : 352;
#pragma unroll
      for (int t = 0; t < 2; ++t) {
        pa[t] = *(const float4*)(ar[t] + kk);
        pb[t] = *(const float4*)(ar[t] + kk + 4);
      }
    }
#pragma unroll
    for (int ni = 0; ni < 8; ++ni) {
      bf16x8 bfv = *(const bf16x8*)(panel + ks * 8192 + ni * 1024 + fb);
      acc[0][ni] = __builtin_amdgcn_mfma_f32_16x16x32_bf16(br0, bfv, acc[0][ni], 0, 0, 0);
      acc[1][ni] = __builtin_amdgcn_mfma_f32_16x16x32_bf16(br1, bfv, acc[1][ni], 0, 0, 0);
    }
  }

  // epilogue: bias+relu, gh1 partial, wave-private transpose, GEMM2 -> packed regs
  float sgh[8];
#pragma unroll
  for (int ni = 0; ni < 8; ++ni) sgh[ni] = 0.f;
  uint2 ph[2][8];
#pragma unroll
  for (int t = 0; t < 2; ++t) {
#pragma unroll
    for (int ni = 0; ni < 8; ++ni) {
      const float bias = b1v[ni];
      float s = 0.f;
#pragma unroll
      for (int r = 0; r < 4; ++r) {
        const int orow = (wid * 2 + t) * 16 + lg * 4 + r;
        float h = acc[t][ni][r] + bias;
        h = h > 0.f ? h : 0.f;
        if (orow >= NN) h = 0.f;
        h1s[(lg * 4 + r) * 136 + ni * 16 + l15] = f2bf(h);
        s += h;
      }
      s += __shfl_xor(s, 16);
      s += __shfl_xor(s, 32);
      sgh[ni] += s;                                  // meaningful on lg==0 lanes
    }
    f32x4 acc2[8];
#pragma unroll
    for (int j = 0; j < 8; ++j) acc2[j] = fz;
#pragma unroll
    for (int ks2 = 0; ks2 < 4; ++ks2) {
      bf16x8 a2 = *(const bf16x8*)&h1s[l15 * 136 + ks2 * 32 + lg * 8];
#pragma unroll
      for (int ni = 0; ni < 8; ++ni) {
        bf16x8 b2f = *(const bf16x8*)(W2T + ks2 * 4096 + ni * 512 + lane * 8);
        acc2[ni] = __builtin_amdgcn_mfma_f32_16x16x32_bf16(a2, b2f, acc2[ni], 0, 0, 0);
      }
    }
#pragma unroll
    for (int ni = 0; ni < 8; ++ni) {
      const unsigned lo = f2bf(acc2[ni][0]) | ((unsigned)f2bf(acc2[ni][1]) << 16);
      const unsigned hi2 = f2bf(acc2[ni][2]) | ((unsigned)f2bf(acc2[ni][3]) << 16);
      ph[t][ni] = make_uint2(lo, hi2);
    }
  }
  if (lg == 0) {
#pragma unroll
    for (int ni = 0; ni < 8; ++ni) ghl[wid * 128 + ni * 16 + l15] = sgh[ni];
  }
  __syncthreads();   // #2: panel1 fully consumed, ghl1 ready

  // overwrite panel with H1W2 (lane holds h'=ni*16+l15, n=(wid*2+t)*16+lg*4+r; b64 packed)
#pragma unroll
  for (int t = 0; t < 2; ++t)
#pragma unroll
    for (int ni = 0; ni < 8; ++ni) {
      char* p2 = panel + wid * 8192 + ni * 1024 + (l15 & 3) * 256 + t * 128 +
                 (l15 >> 2) * 32 + (lg >> 1) * 16 + (lg & 1) * 8;
      *(uint2*)p2 = ph[t][ni];
    }
  if (tid < 128) {
    float s = 0.f;
#pragma unroll
    for (int w = 0; w < 12; ++w) s += ghl[w * 128 + tid];
    gh[b * 256 + tid] = s;
  }
  __syncthreads();   // #3: panel2 (H1W2) ready, ghl free

  // =============== PHASE C: H2 = relu(adj@H1W2+b2) -> out; gh2 =================
#pragma unroll
  for (int t = 0; t < 2; ++t) {
    pa[t] = *(const float4*)(ar[t] + kofs);
    pb[t] = *(const float4*)(ar[t] + kofs + 4);
  }
#pragma unroll
  for (int i = 0; i < 2; ++i)
#pragma unroll
    for (int j = 0; j < 8; ++j) acc[i][j] = fz;

#pragma unroll
  for (int ks = 0; ks < NKS; ++ks) {
    const bool kvalid = (ks * 32 + kofs + 8) <= NN;
    bf16x8 br0 = kvalid ? pack8(pa[0], pb[0]) : bz;
    bf16x8 br1 = kvalid ? pack8(pa[1], pb[1]) : bz;
    if (ks < NKS - 1) {
      int kk = (ks + 1) * 32 + kofs; kk = kk < 352 ? kk : 352;
#pragma unroll
      for (int t = 0; t < 2; ++t) {
        pa[t] = *(const float4*)(ar[t] + kk);
        pb[t] = *(const float4*)(ar[t] + kk + 4);
      }
    }
#pragma unroll
    for (int ni = 0; ni < 8; ++ni) {
      bf16x8 bfv = *(const bf16x8*)(panel + ks * 8192 + ni * 1024 + fb);
      acc[0][ni] = __builtin_amdgcn_mfma_f32_16x16x32_bf16(br0, bfv, acc[0][ni], 0, 0, 0);
      acc[1][ni] = __builtin_amdgcn_mfma_f32_16x16x32_bf16(br1, bfv, acc[1][ni], 0, 0, 0);
    }
  }

  float* outb = out + (size_t)b * NN * NH;
#pragma unroll
  for (int ni = 0; ni < 8; ++ni) sgh[ni] = 0.f;
#pragma unroll
  for (int t = 0; t < 2; ++t) {
#pragma unroll
    for (int ni = 0; ni < 8; ++ni) {
      const float bias = b2v[ni];
      float s = 0.f;
#pragma unroll
      for (int r = 0; r < 4; ++r) {
        const int orow = (wid * 2 + t) * 16 + lg * 4 + r;
        float h = acc[t][ni][r] + bias;
        h = h > 0.f ? h : 0.f;
        if (orow < NN) {
          outb[orow * NH + ni * 16 + l15] = h;
          s += h;
        }
      }
      s += __shfl_xor(s, 16);
      s += __shfl_xor(s, 32);
      sgh[ni] += s;
    }
  }
  if (lg == 0) {
#pragma unroll
    for (int ni = 0; ni < 8; ++ni) ghl[wid * 128 + ni * 16 + l15] = sgh[ni];
  }
  __syncthreads();   // #4: ghl2 ready
  if (tid < 128) {
    float s = 0.f;
#pragma unroll
    for (int w = 0; w < 12; ++w) s += ghl[w * 128 + tid];
    gh[b * 256 + 128 + tid] = s;
  }
}

extern "C" void kernel_launch(void* const* d_in, const int* in_sizes, int n_in,
                              void* d_out, int out_size, void* d_ws, size_t ws_size,
                              hipStream_t stream) {
  const float* x   = (const float*)d_in[0];
  const float* adj = (const float*)d_in[1];
  const float* W1  = (const float*)d_in[2];
  const float* b1  = (const float*)d_in[3];
  const float* W2  = (const float*)d_in[4];
  const float* b2  = (const float*)d_in[5];
  float* out = (float*)d_out;                       // h2 [256,360,128] then gh [256,256]
  float* gh  = out + (size_t)NB * NN * NH;

  char* ws = (char*)d_ws;
  unsigned short* W1T = (unsigned short*)ws;                // 98,304 B
  unsigned short* W2T = (unsigned short*)(ws + 98304);      // 32,768 B

  const int smem_bytes = 98304 + 52224 + 6144;              // 156,672 B
  static int attr_done = 0;
  hipFuncSetAttribute((const void*)k_fused, hipFuncAttributeMaxDynamicSharedMemorySize,
                      smem_bytes);
  (void)attr_done;

  k_prep <<<256, 256, 0, stream>>>(W1, W2, W1T, W2T);
  k_fused<<<NB, 768, smem_bytes, stream>>>(x, adj, W1T, W2T, b1, b2, out, gh);
}

// Round 7
// 116.727 us; speedup vs baseline: 2.7063x; 1.0446x over previous
//
#include <hip/hip_runtime.h>

#define NB 256
#define NN 360
#define NF 360
#define NH 128
#define NKS 12   // 12 k-slices of 32 cover padded 384

using bf16x8 = __attribute__((ext_vector_type(8))) short;
using f32x4  = __attribute__((ext_vector_type(4))) float;

static __device__ __forceinline__ unsigned short f2bf(float f) {
  union { float f; unsigned u; } v; v.f = f;
  unsigned r = v.u + 0x7FFFu + ((v.u >> 16) & 1u);  // RNE
  return (unsigned short)(r >> 16);
}

static __device__ __forceinline__ bf16x8 pack8(float4 a, float4 b) {
  bf16x8 r;
  r[0] = (short)f2bf(a.x); r[1] = (short)f2bf(a.y);
  r[2] = (short)f2bf(a.z); r[3] = (short)f2bf(a.w);
  r[4] = (short)f2bf(b.x); r[5] = (short)f2bf(b.y);
  r[6] = (short)f2bf(b.z); r[7] = (short)f2bf(b.w);
  return r;
}

// chunk-linear tile offset: reader lane (lg*16+l15) gets chunk for (col n=ni*16+l15,
// k j=lg*8..+8) at ni*1024 + lane*16  (contiguous 1 KB/wave read, conflict-free)
static __device__ __forceinline__ int toff(int n, int j) {
  return ((n >> 4) << 10) + ((j >> 3) << 8) + ((n & 15) << 4) + ((j & 7) << 1);
}

// ---------------- K0: build chunk-linear kt-tiles of W1^T and W2^T ----------------------
__global__ void k_prep(const float* __restrict__ W1, const float* __restrict__ W2,
                       unsigned short* __restrict__ W1T, unsigned short* __restrict__ W2T) {
  const int t = blockIdx.x * 256 + threadIdx.x;     // 65536 = 12*4096 + 4*4096
  if (t < NKS * 4096) {
    const int ks = t >> 12, r = t & 4095;
    const int n = r >> 5, j = r & 31;               // n = hidden h, k = feat
    const int k = ks * 32 + j;
    const float v = (k < NF) ? W1[k * NH + n] : 0.f;
    *(unsigned short*)((char*)W1T + ks * 8192 + toff(n, j)) = f2bf(v);
  } else {
    const int t2 = t - NKS * 4096;
    const int ks = t2 >> 12, r = t2 & 4095;
    const int n = r >> 5, j = r & 31;               // n = out hidden, k = in hidden
    const int k = ks * 32 + j;
    *(unsigned short*)((char*)W2T + ks * 8192 + toff(n, j)) = f2bf(W2[k * NH + n]);
  }
}

#define RING_ISSUE(P0, P1, S, KK)                         \
  {                                                       \
    pfa[S][0] = *(const float4*)((P0) + (KK));            \
    pfb[S][0] = *(const float4*)((P0) + (KK) + 4);        \
    pfa[S][1] = *(const float4*)((P1) + (KK));            \
    pfb[S][1] = *(const float4*)((P1) + (KK) + 4);        \
  }

// ---------------- fused per-batch kernel ------------------------------------------------
// LDS: panel 96 KB (phase A: XW1^T tiles; after B: H1W2^T tiles) | h1s 52.2 KB | ghl 6 KB
__global__ __launch_bounds__(768) void k_fused(
    const float* __restrict__ x, const float* __restrict__ adj,
    const unsigned short* __restrict__ W1T, const unsigned short* __restrict__ W2T,
    const float* __restrict__ b1, const float* __restrict__ b2,
    float* __restrict__ out, float* __restrict__ gh) {
  const int b = blockIdx.x;
  const int tid = threadIdx.x;
  const int wid = tid >> 6, lane = tid & 63, l15 = lane & 15, lg = lane >> 4;
  extern __shared__ char smem[];
  char* panel = smem;                                             // 98304 B
  unsigned short* h1s = (unsigned short*)(smem + 98304) + wid * 2176;  // [16][136]/wave
  float* ghl = (float*)(smem + 98304 + 52224);                    // [12][128]

  const int kofs = lg * 8;
  const f32x4 fz = {0.f, 0.f, 0.f, 0.f};
  const bf16x8 bz = {0, 0, 0, 0, 0, 0, 0, 0};

  float b1v[8], b2v[8];
#pragma unroll
  for (int ni = 0; ni < 8; ++ni) {
    b1v[ni] = b1[ni * 16 + l15];
    b2v[ni] = b2[ni * 16 + l15];
  }

  f32x4 acc[2][8];
  float4 pfa[3][2], pfb[3][2];

  // =============== PHASE A: panel = (x@W1)^T ===============
  const int m0 = wid * 32 + l15, m1 = m0 + 16;
  const float* xr0 = x + ((size_t)b * NN + (m0 < NN ? m0 : NN - 1)) * NF;
  const float* xr1 = x + ((size_t)b * NN + (m1 < NN ? m1 : NN - 1)) * NF;

#pragma unroll
  for (int s = 0; s < 3; ++s) {
    int kk = s * 32 + kofs;
    RING_ISSUE(xr0, xr1, s, kk);
  }
#pragma unroll
  for (int i = 0; i < 2; ++i)
#pragma unroll
    for (int j = 0; j < 8; ++j) acc[i][j] = fz;

#pragma unroll
  for (int ks = 0; ks < NKS; ++ks) {
    const int d = ks % 3;
    const bool kv = (ks * 32 + kofs + 8) <= NF;
    bf16x8 br0 = kv ? pack8(pfa[d][0], pfb[d][0]) : bz;
    bf16x8 br1 = kv ? pack8(pfa[d][1], pfb[d][1]) : bz;
    if (ks + 3 < NKS) {
      int kk = (ks + 3) * 32 + kofs; kk = kk < 352 ? kk : 352;
      RING_ISSUE(xr0, xr1, d, kk);
    }
#pragma unroll
    for (int hi = 0; hi < 8; ++hi) {
      bf16x8 af = *(const bf16x8*)(W1T + ks * 4096 + hi * 512 + lane * 8);
      acc[0][hi] = __builtin_amdgcn_mfma_f32_16x16x32_bf16(af, br0, acc[0][hi], 0, 0, 0);
      acc[1][hi] = __builtin_amdgcn_mfma_f32_16x16x32_bf16(af, br1, acc[1][hi], 0, 0, 0);
    }
  }

  // panel1 write: value (h=hi*16+lg*4+r, m=wid*32+t*16+l15) -> tile wid, chunk-linear
  {
    char* pw = panel + wid * 8192 + (l15 >> 3) * 256 + (l15 & 7) * 2;
#pragma unroll
    for (int t = 0; t < 2; ++t) {
      const int m = wid * 32 + t * 16 + l15;
      const bool valid = m < NN;
#pragma unroll
      for (int hi = 0; hi < 8; ++hi)
#pragma unroll
        for (int r = 0; r < 4; ++r)
          *(unsigned short*)(pw + hi * 1024 + t * 512 + (lg * 4 + r) * 16) =
              valid ? f2bf(acc[t][hi][r]) : (unsigned short)0;
    }
  }
  __syncthreads();  // #1: panel1 ready

  // =============== PHASE B: H1 = relu(adj@XW1+b1); H1W2 -> regs ===============
  const float* ar0 = adj + ((size_t)b * NN + (m0 < NN ? m0 : NN - 1)) * NN;
  const float* ar1 = adj + ((size_t)b * NN + (m1 < NN ? m1 : NN - 1)) * NN;

#pragma unroll
  for (int s = 0; s < 3; ++s) {
    int kk = s * 32 + kofs;
    RING_ISSUE(ar0, ar1, s, kk);
  }
#pragma unroll
  for (int i = 0; i < 2; ++i)
#pragma unroll
    for (int j = 0; j < 8; ++j) acc[i][j] = fz;

#pragma unroll
  for (int ks = 0; ks < NKS; ++ks) {
    const int d = ks % 3;
    const bool kv = (ks * 32 + kofs + 8) <= NN;
    bf16x8 br0 = kv ? pack8(pfa[d][0], pfb[d][0]) : bz;
    bf16x8 br1 = kv ? pack8(pfa[d][1], pfb[d][1]) : bz;
    if (ks + 3 < NKS) {
      int kk = (ks + 3) * 32 + kofs; kk = kk < 352 ? kk : 352;
      RING_ISSUE(ar0, ar1, d, kk);
    }
#pragma unroll
    for (int ni = 0; ni < 8; ++ni) {
      bf16x8 bfv = *(const bf16x8*)(panel + ks * 8192 + ni * 1024 + lane * 16);
      acc[0][ni] = __builtin_amdgcn_mfma_f32_16x16x32_bf16(br0, bfv, acc[0][ni], 0, 0, 0);
      acc[1][ni] = __builtin_amdgcn_mfma_f32_16x16x32_bf16(br1, bfv, acc[1][ni], 0, 0, 0);
    }
  }

  // epilogue: bias+relu+mask, gh1 partials, per-wave transpose, GEMM2 -> packed ph
  float sgh[8];
#pragma unroll
  for (int ni = 0; ni < 8; ++ni) sgh[ni] = 0.f;
  unsigned ph[2][8][2];
#pragma unroll
  for (int t = 0; t < 2; ++t) {
#pragma unroll
    for (int ni = 0; ni < 8; ++ni) {
      const float bias = b1v[ni];
      float ssum = 0.f;
#pragma unroll
      for (int r = 0; r < 4; ++r) {
        const int orow = wid * 32 + t * 16 + lg * 4 + r;
        float h = acc[t][ni][r] + bias;
        h = h > 0.f ? h : 0.f;
        if (orow >= NN) h = 0.f;
        h1s[(lg * 4 + r) * 136 + ni * 16 + l15] = f2bf(h);
        ssum += h;
      }
      ssum += __shfl_xor(ssum, 16);
      ssum += __shfl_xor(ssum, 32);
      sgh[ni] += ssum;                               // meaningful on lg==0 lanes
    }
    f32x4 acc2[8];
#pragma unroll
    for (int j = 0; j < 8; ++j) acc2[j] = fz;
#pragma unroll
    for (int ks2 = 0; ks2 < 4; ++ks2) {
      bf16x8 a2 = *(const bf16x8*)&h1s[l15 * 136 + ks2 * 32 + lg * 8];
#pragma unroll
      for (int ni = 0; ni < 8; ++ni) {
        bf16x8 b2f = *(const bf16x8*)(W2T + ks2 * 4096 + ni * 512 + lane * 8);
        acc2[ni] = __builtin_amdgcn_mfma_f32_16x16x32_bf16(a2, b2f, acc2[ni], 0, 0, 0);
      }
    }
#pragma unroll
    for (int ni = 0; ni < 8; ++ni) {
      ph[t][ni][0] = (unsigned)f2bf(acc2[ni][0]) | ((unsigned)f2bf(acc2[ni][1]) << 16);
      ph[t][ni][1] = (unsigned)f2bf(acc2[ni][2]) | ((unsigned)f2bf(acc2[ni][3]) << 16);
    }
  }
  if (lg == 0) {
#pragma unroll
    for (int ni = 0; ni < 8; ++ni) ghl[wid * 128 + ni * 16 + l15] = sgh[ni];
  }
  __syncthreads();  // #2: panel1 fully consumed, ghl1 ready

  // panel2 overwrite: value (n=wid*32+t*16+lg*4+r, j=ni*16+l15), b64 packed (r=0..3)
  {
    char* pw2 = panel + wid * 8192 + (lg >> 1) * 256 + l15 * 16 + (lg & 1) * 8;
#pragma unroll
    for (int t = 0; t < 2; ++t)
#pragma unroll
      for (int ni = 0; ni < 8; ++ni)
        *(uint2*)(pw2 + ni * 1024 + t * 512) = make_uint2(ph[t][ni][0], ph[t][ni][1]);
  }
  if (tid < 128) {
    float s = 0.f;
#pragma unroll
    for (int w = 0; w < 12; ++w) s += ghl[w * 128 + tid];
    gh[b * 256 + tid] = s;
  }
  __syncthreads();  // #3: panel2 ready

  // =============== PHASE C: H2 = relu(adj@H1W2+b2) -> out; gh2 ===============
#pragma unroll
  for (int s = 0; s < 3; ++s) {
    int kk = s * 32 + kofs;
    RING_ISSUE(ar0, ar1, s, kk);
  }
#pragma unroll
  for (int i = 0; i < 2; ++i)
#pragma unroll
    for (int j = 0; j < 8; ++j) acc[i][j] = fz;

#pragma unroll
  for (int ks = 0; ks < NKS; ++ks) {
    const int d = ks % 3;
    const bool kv = (ks * 32 + kofs + 8) <= NN;
    bf16x8 br0 = kv ? pack8(pfa[d][0], pfb[d][0]) : bz;
    bf16x8 br1 = kv ? pack8(pfa[d][1], pfb[d][1]) : bz;
    if (ks + 3 < NKS) {
      int kk = (ks + 3) * 32 + kofs; kk = kk < 352 ? kk : 352;
      RING_ISSUE(ar0, ar1, d, kk);
    }
#pragma unroll
    for (int ni = 0; ni < 8; ++ni) {
      bf16x8 bfv = *(const bf16x8*)(panel + ks * 8192 + ni * 1024 + lane * 16);
      acc[0][ni] = __builtin_amdgcn_mfma_f32_16x16x32_bf16(br0, bfv, acc[0][ni], 0, 0, 0);
      acc[1][ni] = __builtin_amdgcn_mfma_f32_16x16x32_bf16(br1, bfv, acc[1][ni], 0, 0, 0);
    }
  }

  float* outb = out + (size_t)b * NN * NH;
#pragma unroll
  for (int ni = 0; ni < 8; ++ni) sgh[ni] = 0.f;
#pragma unroll
  for (int t = 0; t < 2; ++t) {
#pragma unroll
    for (int ni = 0; ni < 8; ++ni) {
      const float bias = b2v[ni];
      float ssum = 0.f;
#pragma unroll
      for (int r = 0; r < 4; ++r) {
        const int orow = wid * 32 + t * 16 + lg * 4 + r;
        float h = acc[t][ni][r] + bias;
        h = h > 0.f ? h : 0.f;
        if (orow < NN) {
          outb[orow * NH + ni * 16 + l15] = h;
          ssum += h;
        }
      }
      ssum += __shfl_xor(ssum, 16);
      ssum += __shfl_xor(ssum, 32);
      sgh[ni] += ssum;
    }
  }
  if (lg == 0) {
#pragma unroll
    for (int ni = 0; ni < 8; ++ni) ghl[wid * 128 + ni * 16 + l15] = sgh[ni];
  }
  __syncthreads();  // #4
  if (tid < 128) {
    float s = 0.f;
#pragma unroll
    for (int w = 0; w < 12; ++w) s += ghl[w * 128 + tid];
    gh[b * 256 + 128 + tid] = s;
  }
}

extern "C" void kernel_launch(void* const* d_in, const int* in_sizes, int n_in,
                              void* d_out, int out_size, void* d_ws, size_t ws_size,
                              hipStream_t stream) {
  const float* x   = (const float*)d_in[0];
  const float* adj = (const float*)d_in[1];
  const float* W1  = (const float*)d_in[2];
  const float* b1  = (const float*)d_in[3];
  const float* W2  = (const float*)d_in[4];
  const float* b2  = (const float*)d_in[5];
  float* out = (float*)d_out;                       // h2 [256,360,128] then gh [256,256]
  float* gh  = out + (size_t)NB * NN * NH;

  char* ws = (char*)d_ws;
  unsigned short* W1T = (unsigned short*)ws;                // 98,304 B
  unsigned short* W2T = (unsigned short*)(ws + 98304);      // 32,768 B

  const int smem_bytes = 98304 + 52224 + 6144;              // 156,672 B
  hipFuncSetAttribute((const void*)k_fused, hipFuncAttributeMaxDynamicSharedMemorySize,
                      smem_bytes);

  k_prep <<<256, 256, 0, stream>>>(W1, W2, W1T, W2T);
  k_fused<<<NB, 768, smem_bytes, stream>>>(x, adj, W1T, W2T, b1, b2, out, gh);
}